// Round 2
// baseline (205.737 us; speedup 1.0000x reference)
//
#include <hip/hip_runtime.h>
#include <math.h>

#define BN   32
#define CN   256
#define HN   56
#define WN   56
#define HWN  (HN * WN)          // 3136
#define HW4  (HWN / 4)          // 784 float4 quads per spatial plane
#define CHWN (CN * HWN)         // 802816
#define NPOS (BN * HWN)         // 100352
#define NQ   (NPOS / 4)         // 25088 quads total
#define NTOT (BN * CHWN)        // 25690112

typedef float f32x4 __attribute__((ext_vector_type(4)));

// Kernel 1: channel-wise mean & max per spatial position.
//   - float4 over w (16B/lane loads)
//   - 8-way channel split across lane groups (lane>>3 = chunk, lane&7 = quad)
//   - butterfly __shfl_xor combine over lane bits 3..5
// => 3136 waves, ~16x16B in flight per lane: latency-robust.
__global__ __launch_bounds__(256) void sa_reduce_kernel(const f32x4* __restrict__ x4,
                                                        f32x4* __restrict__ avg4,
                                                        f32x4* __restrict__ mx4) {
    int t    = blockIdx.x * 256 + threadIdx.x;
    int wave = t >> 6;
    int lane = t & 63;
    int q     = (wave << 3) | (lane & 7);   // quad index in [0, NQ)
    int chunk = lane >> 3;                  // 8 chunks x 32 channels
    if (q >= NQ) return;                    // exact fit, kept for safety
    int b  = q / HW4;
    int s4 = q - b * HW4;
    const f32x4* xp = x4 + (size_t)b * (CHWN / 4) + (size_t)chunk * 32 * HW4 + s4;

    f32x4 sum = {0.0f, 0.0f, 0.0f, 0.0f};
    f32x4 m   = {-INFINITY, -INFINITY, -INFINITY, -INFINITY};
#pragma unroll 16
    for (int c = 0; c < 32; ++c) {
        f32x4 v = xp[(size_t)c * HW4];
        sum += v;
        m.x = fmaxf(m.x, v.x);
        m.y = fmaxf(m.y, v.y);
        m.z = fmaxf(m.z, v.z);
        m.w = fmaxf(m.w, v.w);
    }
    // combine the 8 channel-chunks: lanes differing in bits 3..5 share a quad
#pragma unroll
    for (int off = 8; off < 64; off <<= 1) {
        sum.x += __shfl_xor(sum.x, off);
        sum.y += __shfl_xor(sum.y, off);
        sum.z += __shfl_xor(sum.z, off);
        sum.w += __shfl_xor(sum.w, off);
        m.x = fmaxf(m.x, __shfl_xor(m.x, off));
        m.y = fmaxf(m.y, __shfl_xor(m.y, off));
        m.z = fmaxf(m.z, __shfl_xor(m.z, off));
        m.w = fmaxf(m.w, __shfl_xor(m.w, off));
    }
    if (chunk == 0) {
        f32x4 a = sum * (1.0f / (float)CN);
        avg4[q] = a;   // lanes 0..7 -> 128B contiguous store
        mx4[q]  = m;
    }
}

// Kernel 2: 7x7 conv over the 2-channel (avg,max) map + sigmoid -> att map.
// Inputs are 0.8 MB -> L2-resident. Compute trivial.
__global__ __launch_bounds__(256) void sa_conv_kernel(const float* __restrict__ avg,
                                                      const float* __restrict__ mx,
                                                      const float* __restrict__ cw,
                                                      float* __restrict__ att) {
    int p = blockIdx.x * blockDim.x + threadIdx.x;
    if (p >= NPOS) return;
    int b = p / HWN;
    int s = p - b * HWN;
    int h = s / WN;
    int w = s - h * WN;
    const float* a0 = avg + b * HWN;
    const float* m0 = mx + b * HWN;
    float acc = 0.0f;
#pragma unroll
    for (int kh = 0; kh < 7; ++kh) {
        int hh = h + kh - 3;
        if (hh < 0 || hh >= HN) continue;
#pragma unroll
        for (int kw = 0; kw < 7; ++kw) {
            int ww = w + kw - 3;
            if (ww < 0 || ww >= WN) continue;
            int idx = hh * WN + ww;
            acc = fmaf(cw[kh * 7 + kw],      a0[idx], acc);
            acc = fmaf(cw[49 + kh * 7 + kw], m0[idx], acc);
        }
    }
    att[p] = 1.0f / (1.0f + expf(-acc));
}

// Kernel 3: out = x * att (broadcast over channels), float4 vectorized.
// 2D grid (plane-quads, batch) removes the /CHWN divide.
// Nontemporal store for out + nontemporal load for x: out is never re-read and
// x is dead after this kernel -> don't let the 102.8MB store stream evict the
// L3-resident copy of x that kernel 1 just established.
__global__ __launch_bounds__(256) void sa_mul_kernel(const f32x4* __restrict__ x4,
                                                     const f32x4* __restrict__ att4,
                                                     f32x4* __restrict__ out4) {
    int b = blockIdx.y;
    int i = blockIdx.x * 256 + threadIdx.x;     // float4 index within batch
    if (i >= CHWN / 4) return;
    int sq = i % HW4;                           // spatial quad (e%HWN)/4
    f32x4 a = att4[(size_t)b * HW4 + sq];       // L2-resident, reused 256x
    size_t gi = (size_t)b * (CHWN / 4) + i;
    f32x4 v = __builtin_nontemporal_load(x4 + gi);
    v *= a;
    __builtin_nontemporal_store(v, out4 + gi);
}

extern "C" void kernel_launch(void* const* d_in, const int* in_sizes, int n_in,
                              void* d_out, int out_size, void* d_ws, size_t ws_size,
                              hipStream_t stream) {
    const float* x  = (const float*)d_in[0];
    const float* cw = (const float*)d_in[1];
    float* out = (float*)d_out;

    float* avg = (float*)d_ws;
    float* mx  = avg + NPOS;
    float* att = mx + NPOS;

    {
        // 8 lane-groups per quad: NQ quads * 8 threads = 200704 threads
        int threads = 256;
        int blocks = (NQ * 8 + threads - 1) / threads;       // 784
        sa_reduce_kernel<<<blocks, threads, 0, stream>>>(
            (const f32x4*)x, (f32x4*)avg, (f32x4*)mx);
    }
    {
        int threads = 256;
        int blocks = (NPOS + threads - 1) / threads;         // 392
        sa_conv_kernel<<<blocks, threads, 0, stream>>>(avg, mx, cw, att);
    }
    {
        dim3 grid(CHWN / 4 / 256, BN);                       // (784, 32)
        sa_mul_kernel<<<grid, 256, 0, stream>>>(
            (const f32x4*)x, (const f32x4*)att, (f32x4*)out);
    }
}